// Round 1
// baseline (305.361 us; speedup 1.0000x reference)
//
#include <hip/hip_runtime.h>

// 3-layer GraphSAGE, N=100000, F=H=128, E=1.6M.
// bf16 features, weights hi/lo split -> 2-term MFMA, Z=[agg|root] layout.
// One-pass slab CSR build; fused prep kernel; zero-row padded gather.
// THIS VERSION: aggregation fused into the MFMA layer kernel (k_fused):
//   each wave gathers+means its own 64 output rows into a bank-swizzled
//   LDS tile (2-node ILP), one barrier, then the MFMA body reads the agg
//   half from LDS. Removes agg global write+read (2x51 MB) and 2 launches.

#define NN 100000
#define NB 391          // ceil(100000/256) buckets of 256 dst nodes
#define SLAB 5120       // slab capacity per bucket (mean 4096, sigma 64)

typedef short bf16x8 __attribute__((ext_vector_type(8)));
typedef float f32x4 __attribute__((ext_vector_type(4)));

static __device__ __forceinline__ float uaf(unsigned u) { return __uint_as_float(u); }
static __device__ __forceinline__ unsigned short f2bf(float f) {
  unsigned u = __float_as_uint(f);
  u += 0x7fffu + ((u >> 16) & 1u);
  return (unsigned short)(u >> 16);
}

// ---------------- fused prep: scatter | cvt_x | cvt_w | zero rows ----------------
__global__ __launch_bounds__(256) void k_prep(
    const int* __restrict__ src, const int* __restrict__ dst, int E, int SB,
    int* __restrict__ cursor, unsigned* __restrict__ pairs,
    const float* __restrict__ x, unsigned short* __restrict__ Z1,
    unsigned short* __restrict__ Z2,
    const float* __restrict__ W1l, const float* __restrict__ W1r,
    const float* __restrict__ W2l, const float* __restrict__ W2r,
    unsigned short* __restrict__ wt1h, unsigned short* __restrict__ wt1l,
    unsigned short* __restrict__ wt2h, unsigned short* __restrict__ wt2l) {
  __shared__ int h[NB];
  __shared__ int rb[NB];
  const int b = blockIdx.x;
  const int tid = threadIdx.x;
  const int XB = NN * 16 / 256;  // 6250 cvt_x blocks

  if (b < SB) {
    // ---- edge scatter into bucket slabs ----
    for (int i = tid; i < NB; i += 256) h[i] = 0;
    __syncthreads();
    int s[8], d[8];
    const int base = b * 2048 + tid * 8;
    #pragma unroll
    for (int i = 0; i < 8; i++) {
      int g = base + i;
      bool ok = g < E;
      s[i] = ok ? src[g] : 0;
      d[i] = ok ? dst[g] : -1;
      if (ok) atomicAdd(&h[d[i] >> 8], 1);
    }
    __syncthreads();
    for (int i = tid; i < NB; i += 256) {
      rb[i] = h[i] ? atomicAdd(&cursor[i], h[i]) : 0;
      h[i] = 0;
    }
    __syncthreads();
    #pragma unroll
    for (int i = 0; i < 8; i++) {
      if (d[i] >= 0) {
        int bk = d[i] >> 8;
        int off = rb[bk] + atomicAdd(&h[bk], 1);
        if (off < SLAB)
          pairs[(size_t)bk * SLAB + off] =
              ((unsigned)(d[i] & 255) << 17) | (unsigned)s[i];
      }
    }
  } else if (b < SB + XB) {
    // ---- x fp32 -> bf16 into Z1 root half ----
    int t = (b - SB) * 256 + tid;      // t < N*16
    int node = t >> 4, c = t & 15;
    const float4* xp = (const float4*)(x + (size_t)node * 128 + c * 8);
    float4 a = xp[0], bb = xp[1];
    float v[8] = {a.x, a.y, a.z, a.w, bb.x, bb.y, bb.z, bb.w};
    unsigned hh[8];
    #pragma unroll
    for (int i = 0; i < 8; i++) hh[i] = f2bf(v[i]);
    uint4 p;
    p.x = hh[0] | (hh[1] << 16); p.y = hh[2] | (hh[3] << 16);
    p.z = hh[4] | (hh[5] << 16); p.w = hh[6] | (hh[7] << 16);
    *(uint4*)(Z1 + (size_t)node * 256 + 128 + c * 8) = p;
  } else if (b < SB + XB + 64) {
    // ---- weight transpose + hi/lo split ----
    #pragma unroll
    for (int it = 0; it < 4; it++) {
      int t = (b - SB - XB) * 1024 + it * 256 + tid;  // t < 65536
      int layer = t >> 15;
      int rem = t & 32767;
      int k = rem >> 7;
      int nn = rem & 127;
      const float* Wl = layer ? W2l : W1l;
      const float* Wr = layer ? W2r : W1r;
      float v = (k < 128) ? Wl[k * 128 + nn] : Wr[(k - 128) * 128 + nn];
      unsigned short hv = f2bf(v);
      unsigned short lv = f2bf(v - uaf(((unsigned)hv) << 16));
      (layer ? wt2h : wt1h)[nn * 256 + k] = hv;
      (layer ? wt2l : wt1l)[nn * 256 + k] = lv;
    }
  } else {
    // ---- zero row N of Z1/Z2 (padding row for gather) ----
    unsigned* z1r = (unsigned*)(Z1 + (size_t)NN * 256);
    unsigned* z2r = (unsigned*)(Z2 + (size_t)NN * 256);
    if (tid < 128) z1r[tid] = 0;
    else z2r[tid - 128] = 0;
  }
}

// ---------------- per-bucket CSR build ----------------
__global__ __launch_bounds__(256) void k_build(const unsigned* __restrict__ pairs,
                                               const int* __restrict__ cursor,
                                               int* __restrict__ beg, int* __restrict__ deg,
                                               int* __restrict__ csr, int N) {
  __shared__ int cnt[256];
  __shared__ int sd[256];
  __shared__ int cur[256];
  const int b = blockIdx.x;
  const int tid = threadIdx.x;
  const size_t p0 = (size_t)b * SLAB;
  int count = cursor[b];
  if (count > SLAB) count = SLAB;
  cnt[tid] = 0;
  cur[tid] = 0;
  __syncthreads();
  for (int i = tid; i < count; i += 256) atomicAdd(&cnt[pairs[p0 + i] >> 17], 1);
  __syncthreads();
  int v = cnt[tid];
  sd[tid] = v;
  __syncthreads();
  #pragma unroll
  for (int off = 1; off < 256; off <<= 1) {
    int u = (tid >= off) ? sd[tid - off] : 0;
    __syncthreads();
    sd[tid] += u;
    __syncthreads();
  }
  const int node = b * 256 + tid;
  if (node < N) {
    beg[node] = (int)p0 + (sd[tid] - v);
    deg[node] = v;
  }
  __syncthreads();
  for (int i = tid; i < count; i += 256) {
    unsigned pv = pairs[p0 + i];
    int dl = pv >> 17;
    int pos = (sd[dl] - cnt[dl]) + atomicAdd(&cur[dl], 1);
    csr[p0 + pos] = pv & 0x1ffff;
  }
}

// accumulate 8 bf16 (packed in uint4) into float acc[8] -- bit-exact same as before
#define ACC8(A, v)                                \
  A[0] += uaf((v).x << 16);                       \
  A[1] += uaf((v).x & 0xffff0000u);               \
  A[2] += uaf((v).y << 16);                       \
  A[3] += uaf((v).y & 0xffff0000u);               \
  A[4] += uaf((v).z << 16);                       \
  A[5] += uaf((v).z & 0xffff0000u);               \
  A[6] += uaf((v).w << 16);                       \
  A[7] += uaf((v).w & 0xffff0000u);

// ---------------- fused: per-wave gather+mean (LDS) -> MFMA layer ----------------
// MODE 0: out = relu([agg|root]@W + b) bf16 -> outB[node*256 + 128 + f] (Z2 root)
// MODE 1: h = relu(...) fp32 regs; s2 = h.w3l, r2 = h.w3r (fused layer 3)
template <int MODE>
__global__ __launch_bounds__(256, 2) void k_fused(
    const unsigned short* __restrict__ Z,   // gather source + root half
    const int* __restrict__ begA, const int* __restrict__ degA,
    const int* __restrict__ csr,
    const unsigned short* __restrict__ WTh, const unsigned short* __restrict__ WTl,
    const float* __restrict__ bias, unsigned short* __restrict__ outB,
    const float* __restrict__ w3l, const float* __restrict__ w3r,
    float* __restrict__ s2, float* __restrict__ r2, int n) {
  // 256 rows x 128 bf16 agg tile, XOR-swizzled 16B slots (G4 fix for the
  // stride-256B column reads in phase 2: 16-way -> 2-way).
  __shared__ __align__(16) unsigned short smem[256 * 128];  // 64 KB
  const int tid = threadIdx.x;
  const int lane = tid & 63;
  const int w = tid >> 6;
  const int g = lane >> 4, c = lane & 15;
  const int blk0 = blockIdx.x * 256;

  // ---------- phase 1: gather + mean for this wave's 64 rows (2-node ILP) ----------
  for (int ii = 0; ii < 64; ii += 2) {
    const int nd0 = blk0 + w * 64 + ii;
    const int nd1 = nd0 + 1;
    int dg0 = 0, bg0 = 0, dg1 = 0, bg1 = 0;
    if (nd0 < n) { dg0 = degA[nd0]; bg0 = begA[nd0]; }
    if (nd1 < n) { dg1 = degA[nd1]; bg1 = begA[nd1]; }
    float acc0[8] = {0.f, 0.f, 0.f, 0.f, 0.f, 0.f, 0.f, 0.f};
    float acc1[8] = {0.f, 0.f, 0.f, 0.f, 0.f, 0.f, 0.f, 0.f};
    const int dmax = dg0 > dg1 ? dg0 : dg1;

    for (int base = 0; base < dmax; base += 64) {
      int m0v = dg0 - base; if (m0v > 64) m0v = 64;   // may be <= 0: fully masked
      int m1v = dg1 - base; if (m1v > 64) m1v = 64;
      int i0 = csr[bg0 + base + (lane < m0v ? lane : 0)];
      int i1 = csr[bg1 + base + (lane < m1v ? lane : 0)];
      const int mm = m0v > m1v ? m0v : m1v;
      for (int k = 0; k < mm; k += 32) {
        uint4 vA0[4], vA1[4], vB0[4], vB1[4];
        const bool hB0 = (k + 16) < m0v;
        const bool hB1 = (k + 16) < m1v;
        #pragma unroll
        for (int u = 0; u < 4; u++) {
          int kk = k + u * 4 + g;
          int j0 = __shfl(i0, kk & 63); j0 = (kk < m0v) ? j0 : NN;  // zero row
          int j1 = __shfl(i1, kk & 63); j1 = (kk < m1v) ? j1 : NN;
          vA0[u] = *(const uint4*)(Z + (size_t)j0 * 256 + 128 + c * 8);
          vA1[u] = *(const uint4*)(Z + (size_t)j1 * 256 + 128 + c * 8);
        }
        if (hB0 | hB1) {
          #pragma unroll
          for (int u = 0; u < 4; u++) {
            int kk = k + 16 + u * 4 + g;
            int j0 = __shfl(i0, kk & 63); j0 = (kk < m0v) ? j0 : NN;
            int j1 = __shfl(i1, kk & 63); j1 = (kk < m1v) ? j1 : NN;
            vB0[u] = *(const uint4*)(Z + (size_t)j0 * 256 + 128 + c * 8);
            vB1[u] = *(const uint4*)(Z + (size_t)j1 * 256 + 128 + c * 8);
          }
        }
        #pragma unroll
        for (int u = 0; u < 4; u++) { ACC8(acc0, vA0[u]); ACC8(acc1, vA1[u]); }
        if (hB0 | hB1) {
          #pragma unroll
          for (int u = 0; u < 4; u++) { ACC8(acc0, vB0[u]); ACC8(acc1, vB1[u]); }
        }
      }
    }
    #pragma unroll
    for (int j = 0; j < 8; j++) {
      acc0[j] += __shfl_xor(acc0[j], 16);
      acc0[j] += __shfl_xor(acc0[j], 32);
      acc1[j] += __shfl_xor(acc1[j], 16);
      acc1[j] += __shfl_xor(acc1[j], 32);
    }
    const float inv0 = dg0 > 0 ? 1.0f / (float)dg0 : 0.f;
    const float inv1 = dg1 > 0 ? 1.0f / (float)dg1 : 0.f;
    if (g == 0) {
      unsigned h0[8], h1[8];
      #pragma unroll
      for (int j = 0; j < 8; j++) {
        h0[j] = f2bf(acc0[j] * inv0);
        h1[j] = f2bf(acc1[j] * inv1);
      }
      uint4 p0, p1;
      p0.x = h0[0] | (h0[1] << 16); p0.y = h0[2] | (h0[3] << 16);
      p0.z = h0[4] | (h0[5] << 16); p0.w = h0[6] | (h0[7] << 16);
      p1.x = h1[0] | (h1[1] << 16); p1.y = h1[2] | (h1[3] << 16);
      p1.z = h1[4] | (h1[5] << 16); p1.w = h1[6] | (h1[7] << 16);
      const int r0 = w * 64 + ii, r1 = r0 + 1;
      *(uint4*)((char*)smem + r0 * 256 + ((c * 16) ^ ((r0 & 7) << 4))) = p0;
      *(uint4*)((char*)smem + r1 * 256 + ((c * 16) ^ ((r1 & 7) << 4))) = p1;
    }
  }

  __syncthreads();

  // ---------- phase 2: MFMA layer (agg half from LDS, root half from global) ----------
  {
    const int ln = c;
    const int r16 = g;
    const int m0 = blk0 + w * 64;

    f32x4 acc[4][8];
    #pragma unroll
    for (int s = 0; s < 4; s++)
      #pragma unroll
      for (int cc = 0; cc < 8; cc++) {
        acc[s][cc][0] = 0.f; acc[s][cc][1] = 0.f;
        acc[s][cc][2] = 0.f; acc[s][cc][3] = 0.f;
      }
    float bv[8];
    #pragma unroll
    for (int cc = 0; cc < 8; cc++) bv[cc] = bias[cc * 16 + ln];

    const size_t wbase = (size_t)ln * 256 + r16 * 8;

    #pragma unroll
    for (int kh = 0; kh < 2; kh++) {
      bf16x8 a[4][4];
      #pragma unroll
      for (int s = 0; s < 4; s++) {
        if (kh == 0) {
          const int rl = w * 64 + s * 16 + ln;
          const char* lp = (const char*)smem + rl * 256;
          #pragma unroll
          for (int ks = 0; ks < 4; ks++)
            a[s][ks] = *(const bf16x8*)(lp + ((ks * 64 + r16 * 16) ^ ((rl & 7) << 4)));
        } else {
          int row = m0 + s * 16 + ln;
          if (row > n - 1) row = n - 1;
          const unsigned short* zp = Z + (size_t)row * 256 + 128 + r16 * 8;
          #pragma unroll
          for (int ks = 0; ks < 4; ks++) a[s][ks] = *(const bf16x8*)(zp + ks * 32);
        }
      }
      #pragma unroll
      for (int ks = 0; ks < 4; ks++) {
        #pragma unroll
        for (int cg = 0; cg < 4; cg++) {
          bf16x8 bh[2], bl[2];
          #pragma unroll
          for (int j = 0; j < 2; j++) {
            const size_t o = wbase + (size_t)(cg * 2 + j) * 4096 + kh * 128 + ks * 32;
            bh[j] = *(const bf16x8*)(WTh + o);
            bl[j] = *(const bf16x8*)(WTl + o);
          }
          #pragma unroll
          for (int j = 0; j < 2; j++) {
            #pragma unroll
            for (int s = 0; s < 4; s++) {
              acc[s][cg * 2 + j] =
                  __builtin_amdgcn_mfma_f32_16x16x32_bf16(a[s][ks], bh[j], acc[s][cg * 2 + j], 0, 0, 0);
              acc[s][cg * 2 + j] =
                  __builtin_amdgcn_mfma_f32_16x16x32_bf16(a[s][ks], bl[j], acc[s][cg * 2 + j], 0, 0, 0);
            }
          }
        }
      }
    }

    if (MODE == 0) {
      #pragma unroll
      for (int s = 0; s < 4; s++)
        #pragma unroll
        for (int r = 0; r < 4; r++) {
          int node = m0 + s * 16 + r16 * 4 + r;
          if (node < n) {
            unsigned short* op = outB + (size_t)node * 256 + 128 + ln;
            #pragma unroll
            for (int cc = 0; cc < 8; cc++) {
              float v = fmaxf(acc[s][cc][r] + bv[cc], 0.f);
              op[cc * 16] = f2bf(v);
            }
          }
        }
    } else {
      float wl[8], wr[8];
      #pragma unroll
      for (int cc = 0; cc < 8; cc++) {
        wl[cc] = w3l[cc * 16 + ln];
        wr[cc] = w3r[cc * 16 + ln];
      }
      #pragma unroll
      for (int s = 0; s < 4; s++)
        #pragma unroll
        for (int r = 0; r < 4; r++) {
          float sl = 0.f, sr = 0.f;
          #pragma unroll
          for (int cc = 0; cc < 8; cc++) {
            float v = fmaxf(acc[s][cc][r] + bv[cc], 0.f);
            sl += v * wl[cc];
            sr += v * wr[cc];
          }
          sl += __shfl_xor(sl, 1); sl += __shfl_xor(sl, 2);
          sl += __shfl_xor(sl, 4); sl += __shfl_xor(sl, 8);
          sr += __shfl_xor(sr, 1); sr += __shfl_xor(sr, 2);
          sr += __shfl_xor(sr, 4); sr += __shfl_xor(sr, 8);
          int node = m0 + s * 16 + r16 * 4 + r;
          if (ln == 0 && node < n) {
            s2[node] = sl;
            r2[node] = sr;
          }
        }
    }
  }
}

// ---------------- final scalar aggregation (16 lanes/node) ----------------
__global__ __launch_bounds__(256) void k_out3(const float* __restrict__ s2,
                                              const float* __restrict__ r2,
                                              const int* __restrict__ beg,
                                              const int* __restrict__ deg,
                                              const int* __restrict__ csr,
                                              const float* __restrict__ b3,
                                              float* __restrict__ out, int n) {
  int t = blockIdx.x * blockDim.x + threadIdx.x;
  int node = t >> 4;
  int ln = t & 15;
  if (node >= n) return;
  int bg = beg[node], d = deg[node];
  float s = 0.f;
  for (int i = ln; i < d; i += 16) s += s2[csr[bg + i]];
  s += __shfl_xor(s, 1); s += __shfl_xor(s, 2);
  s += __shfl_xor(s, 4); s += __shfl_xor(s, 8);
  if (ln == 0) out[node] = s / (d > 0 ? (float)d : 1.0f) + r2[node] + b3[0];
}

extern "C" void kernel_launch(void* const* d_in, const int* in_sizes, int n_in,
                              void* d_out, int out_size, void* d_ws, size_t ws_size,
                              hipStream_t stream) {
  const float* x   = (const float*)d_in[0];
  const int*   ei  = (const int*)d_in[1];
  const float* W1l = (const float*)d_in[2];
  const float* W1r = (const float*)d_in[3];
  const float* b1  = (const float*)d_in[4];
  const float* W2l = (const float*)d_in[5];
  const float* W2r = (const float*)d_in[6];
  const float* b2  = (const float*)d_in[7];
  const float* W3l = (const float*)d_in[8];
  const float* W3r = (const float*)d_in[9];
  const float* b3  = (const float*)d_in[10];
  float* out = (float*)d_out;

  const int N = NN;
  const int E = in_sizes[1] / 2;
  const int* src = ei;
  const int* dst = ei + E;

  char* ws = (char*)d_ws;
  size_t off = 0;
  auto alloc = [&](size_t bytes) -> char* {
    char* p = ws + off;
    off = (off + bytes + 255) & ~(size_t)255;
    return p;
  };
  int* cursor = (int*)alloc((NB + 1) * 4);
  unsigned* pairs = (unsigned*)alloc((size_t)NB * SLAB * 4);
  int* csr  = (int*)alloc((size_t)NB * SLAB * 4);
  int* beg  = (int*)alloc((size_t)N * 4);
  int* deg  = (int*)alloc((size_t)N * 4);
  float* s2 = (float*)alloc((size_t)N * 4);
  float* r2 = (float*)alloc((size_t)N * 4);
  unsigned short* wt1h = (unsigned short*)alloc(128 * 256 * 2);
  unsigned short* wt1l = (unsigned short*)alloc(128 * 256 * 2);
  unsigned short* wt2h = (unsigned short*)alloc(128 * 256 * 2);
  unsigned short* wt2l = (unsigned short*)alloc(128 * 256 * 2);
  unsigned short* Z1 = (unsigned short*)alloc((size_t)(N + 1) * 256 * 2);
  unsigned short* Z2 = (unsigned short*)alloc((size_t)(N + 1) * 256 * 2);

  hipMemsetAsync(cursor, 0, (NB + 1) * 4, stream);

  // ---- fused prep: edge scatter | x->bf16 | weight split | zero rows ----
  const int SB = (E + 2047) / 2048;         // 782 scatter blocks
  const int XB = N * 16 / 256;              // 6250 cvt_x blocks
  k_prep<<<SB + XB + 64 + 1, 256, 0, stream>>>(
      src, dst, E, SB, cursor, pairs, x, Z1, Z2,
      W1l, W1r, W2l, W2r, wt1h, wt1l, wt2h, wt2l);
  k_build<<<NB, 256, 0, stream>>>(pairs, cursor, beg, deg, csr, N);

  const int sb = (N + 255) / 256;
  // ---- layer 1 (gather + GEMM fused) ----
  k_fused<0><<<sb, 256, 0, stream>>>(Z1, beg, deg, csr, wt1h, wt1l, b1, Z2,
                                     nullptr, nullptr, nullptr, nullptr, N);
  // ---- layer 2 (gather + GEMM + fused layer-3 transform) ----
  k_fused<1><<<sb, 256, 0, stream>>>(Z2, beg, deg, csr, wt2h, wt2l, b2, nullptr,
                                     W3l, W3r, s2, r2, N);
  // ---- layer 3 scalar aggregation ----
  k_out3<<<(N * 16 + 255) / 256, 256, 0, stream>>>(s2, r2, beg, deg, csr, b3, out, N);
}

// Round 2
// 289.955 us; speedup vs baseline: 1.0531x; 1.0531x over previous
//
#include <hip/hip_runtime.h>

// 3-layer GraphSAGE, N=100000, F=H=128, E=1.6M.
// bf16 features, weights hi/lo split -> 2-term MFMA, Z=[agg|root] layout.
// One-pass slab CSR build; fused prep kernel; zero-row padded gather.
// THIS VERSION: reverted the aggregation/GEMM fusion (occupancy collapse,
// gather is latency-bound). k_aggZ now processes TWO nodes per wave
// (2-node ILP -> 8 outstanding gather loads/wave instead of 4) to raise
// the outstanding-load product that the random-row miss path scales with.

#define NN 100000
#define NB 391          // ceil(100000/256) buckets of 256 dst nodes
#define SLAB 5120       // slab capacity per bucket (mean 4096, sigma 64)

typedef short bf16x8 __attribute__((ext_vector_type(8)));
typedef float f32x4 __attribute__((ext_vector_type(4)));

static __device__ __forceinline__ float uaf(unsigned u) { return __uint_as_float(u); }
static __device__ __forceinline__ unsigned short f2bf(float f) {
  unsigned u = __float_as_uint(f);
  u += 0x7fffu + ((u >> 16) & 1u);
  return (unsigned short)(u >> 16);
}

// ---------------- fused prep: scatter | cvt_x | cvt_w | zero rows ----------------
__global__ __launch_bounds__(256) void k_prep(
    const int* __restrict__ src, const int* __restrict__ dst, int E, int SB,
    int* __restrict__ cursor, unsigned* __restrict__ pairs,
    const float* __restrict__ x, unsigned short* __restrict__ Z1,
    unsigned short* __restrict__ Z2,
    const float* __restrict__ W1l, const float* __restrict__ W1r,
    const float* __restrict__ W2l, const float* __restrict__ W2r,
    unsigned short* __restrict__ wt1h, unsigned short* __restrict__ wt1l,
    unsigned short* __restrict__ wt2h, unsigned short* __restrict__ wt2l) {
  __shared__ int h[NB];
  __shared__ int rb[NB];
  const int b = blockIdx.x;
  const int tid = threadIdx.x;
  const int XB = NN * 16 / 256;  // 6250 cvt_x blocks

  if (b < SB) {
    // ---- edge scatter into bucket slabs ----
    for (int i = tid; i < NB; i += 256) h[i] = 0;
    __syncthreads();
    int s[8], d[8];
    const int base = b * 2048 + tid * 8;
    #pragma unroll
    for (int i = 0; i < 8; i++) {
      int g = base + i;
      bool ok = g < E;
      s[i] = ok ? src[g] : 0;
      d[i] = ok ? dst[g] : -1;
      if (ok) atomicAdd(&h[d[i] >> 8], 1);
    }
    __syncthreads();
    for (int i = tid; i < NB; i += 256) {
      rb[i] = h[i] ? atomicAdd(&cursor[i], h[i]) : 0;
      h[i] = 0;
    }
    __syncthreads();
    #pragma unroll
    for (int i = 0; i < 8; i++) {
      if (d[i] >= 0) {
        int bk = d[i] >> 8;
        int off = rb[bk] + atomicAdd(&h[bk], 1);
        if (off < SLAB)
          pairs[(size_t)bk * SLAB + off] =
              ((unsigned)(d[i] & 255) << 17) | (unsigned)s[i];
      }
    }
  } else if (b < SB + XB) {
    // ---- x fp32 -> bf16 into Z1 root half ----
    int t = (b - SB) * 256 + tid;      // t < N*16
    int node = t >> 4, c = t & 15;
    const float4* xp = (const float4*)(x + (size_t)node * 128 + c * 8);
    float4 a = xp[0], bb = xp[1];
    float v[8] = {a.x, a.y, a.z, a.w, bb.x, bb.y, bb.z, bb.w};
    unsigned hh[8];
    #pragma unroll
    for (int i = 0; i < 8; i++) hh[i] = f2bf(v[i]);
    uint4 p;
    p.x = hh[0] | (hh[1] << 16); p.y = hh[2] | (hh[3] << 16);
    p.z = hh[4] | (hh[5] << 16); p.w = hh[6] | (hh[7] << 16);
    *(uint4*)(Z1 + (size_t)node * 256 + 128 + c * 8) = p;
  } else if (b < SB + XB + 64) {
    // ---- weight transpose + hi/lo split ----
    #pragma unroll
    for (int it = 0; it < 4; it++) {
      int t = (b - SB - XB) * 1024 + it * 256 + tid;  // t < 65536
      int layer = t >> 15;
      int rem = t & 32767;
      int k = rem >> 7;
      int nn = rem & 127;
      const float* Wl = layer ? W2l : W1l;
      const float* Wr = layer ? W2r : W1r;
      float v = (k < 128) ? Wl[k * 128 + nn] : Wr[(k - 128) * 128 + nn];
      unsigned short hv = f2bf(v);
      unsigned short lv = f2bf(v - uaf(((unsigned)hv) << 16));
      (layer ? wt2h : wt1h)[nn * 256 + k] = hv;
      (layer ? wt2l : wt1l)[nn * 256 + k] = lv;
    }
  } else {
    // ---- zero row N of Z1/Z2 (padding row for gather) ----
    unsigned* z1r = (unsigned*)(Z1 + (size_t)NN * 256);
    unsigned* z2r = (unsigned*)(Z2 + (size_t)NN * 256);
    if (tid < 128) z1r[tid] = 0;
    else z2r[tid - 128] = 0;
  }
}

// ---------------- per-bucket CSR build ----------------
__global__ __launch_bounds__(256) void k_build(const unsigned* __restrict__ pairs,
                                               const int* __restrict__ cursor,
                                               int* __restrict__ beg, int* __restrict__ deg,
                                               int* __restrict__ csr, int N) {
  __shared__ int cnt[256];
  __shared__ int sd[256];
  __shared__ int cur[256];
  const int b = blockIdx.x;
  const int tid = threadIdx.x;
  const size_t p0 = (size_t)b * SLAB;
  int count = cursor[b];
  if (count > SLAB) count = SLAB;
  cnt[tid] = 0;
  cur[tid] = 0;
  __syncthreads();
  for (int i = tid; i < count; i += 256) atomicAdd(&cnt[pairs[p0 + i] >> 17], 1);
  __syncthreads();
  int v = cnt[tid];
  sd[tid] = v;
  __syncthreads();
  #pragma unroll
  for (int off = 1; off < 256; off <<= 1) {
    int u = (tid >= off) ? sd[tid - off] : 0;
    __syncthreads();
    sd[tid] += u;
    __syncthreads();
  }
  const int node = b * 256 + tid;
  if (node < N) {
    beg[node] = (int)p0 + (sd[tid] - v);
    deg[node] = v;
  }
  __syncthreads();
  for (int i = tid; i < count; i += 256) {
    unsigned pv = pairs[p0 + i];
    int dl = pv >> 17;
    int pos = (sd[dl] - cnt[dl]) + atomicAdd(&cur[dl], 1);
    csr[p0 + pos] = pv & 0x1ffff;
  }
}

// accumulate 8 bf16 (packed in uint4) into float A[8] -- bit-exact unpack order
#define ACC8(A, v)                                \
  A[0] += uaf((v).x << 16);                       \
  A[1] += uaf((v).x & 0xffff0000u);               \
  A[2] += uaf((v).y << 16);                       \
  A[3] += uaf((v).y & 0xffff0000u);               \
  A[4] += uaf((v).z << 16);                       \
  A[5] += uaf((v).z & 0xffff0000u);               \
  A[6] += uaf((v).w << 16);                       \
  A[7] += uaf((v).w & 0xffff0000u);

// ---------------- mean aggregation over Z root halves (2 nodes / wave) ----------------
__global__ __launch_bounds__(256) void k_aggZ(unsigned short* __restrict__ Z,
                                              const int* __restrict__ begA,
                                              const int* __restrict__ degA,
                                              const int* __restrict__ csr,
                                              int nPairs, int n) {
  const int wid = (blockIdx.x * blockDim.x + threadIdx.x) >> 6;  // pair id
  const int lane = threadIdx.x & 63;
  if (wid >= nPairs) return;
  const int nd0 = wid * 2;
  const int nd1 = nd0 + 1;
  const int g = lane >> 4, c = lane & 15;

  int dg0 = degA[nd0], bg0 = begA[nd0];
  int dg1 = 0, bg1 = bg0;
  if (nd1 < n) { dg1 = degA[nd1]; bg1 = begA[nd1]; }

  float acc0[8] = {0.f, 0.f, 0.f, 0.f, 0.f, 0.f, 0.f, 0.f};
  float acc1[8] = {0.f, 0.f, 0.f, 0.f, 0.f, 0.f, 0.f, 0.f};
  const int dmax = dg0 > dg1 ? dg0 : dg1;

  for (int base = 0; base < dmax; base += 64) {
    int m0v = dg0 - base; if (m0v > 64) m0v = 64;   // may be <= 0: fully masked
    int m1v = dg1 - base; if (m1v > 64) m1v = 64;
    int i0 = csr[bg0 + base + (lane < m0v ? lane : 0)];
    int i1 = csr[bg1 + base + (lane < m1v ? lane : 0)];
    const int mm = m0v > m1v ? m0v : m1v;
    for (int k = 0; k < mm; k += 32) {
      uint4 vA0[4], vA1[4], vB0[4], vB1[4];
      const bool hB0 = (k + 16) < m0v;
      const bool hB1 = (k + 16) < m1v;
      #pragma unroll
      for (int u = 0; u < 4; u++) {
        int kk = k + u * 4 + g;
        int j0 = __shfl(i0, kk & 63); j0 = (kk < m0v) ? j0 : NN;  // zero row
        int j1 = __shfl(i1, kk & 63); j1 = (kk < m1v) ? j1 : NN;
        vA0[u] = *(const uint4*)(Z + (size_t)j0 * 256 + 128 + c * 8);
        vA1[u] = *(const uint4*)(Z + (size_t)j1 * 256 + 128 + c * 8);
      }
      if (hB0 | hB1) {
        #pragma unroll
        for (int u = 0; u < 4; u++) {
          int kk = k + 16 + u * 4 + g;
          int j0 = __shfl(i0, kk & 63); j0 = (kk < m0v) ? j0 : NN;
          int j1 = __shfl(i1, kk & 63); j1 = (kk < m1v) ? j1 : NN;
          vB0[u] = *(const uint4*)(Z + (size_t)j0 * 256 + 128 + c * 8);
          vB1[u] = *(const uint4*)(Z + (size_t)j1 * 256 + 128 + c * 8);
        }
      }
      #pragma unroll
      for (int u = 0; u < 4; u++) { ACC8(acc0, vA0[u]); ACC8(acc1, vA1[u]); }
      if (hB0 | hB1) {
        #pragma unroll
        for (int u = 0; u < 4; u++) { ACC8(acc0, vB0[u]); ACC8(acc1, vB1[u]); }
      }
    }
  }
  #pragma unroll
  for (int j = 0; j < 8; j++) {
    acc0[j] += __shfl_xor(acc0[j], 16);
    acc0[j] += __shfl_xor(acc0[j], 32);
    acc1[j] += __shfl_xor(acc1[j], 16);
    acc1[j] += __shfl_xor(acc1[j], 32);
  }
  const float inv0 = dg0 > 0 ? 1.0f / (float)dg0 : 0.f;
  const float inv1 = dg1 > 0 ? 1.0f / (float)dg1 : 0.f;
  if (g == 0) {
    unsigned h0[8], h1[8];
    #pragma unroll
    for (int j = 0; j < 8; j++) {
      h0[j] = f2bf(acc0[j] * inv0);
      h1[j] = f2bf(acc1[j] * inv1);
    }
    uint4 p0, p1;
    p0.x = h0[0] | (h0[1] << 16); p0.y = h0[2] | (h0[3] << 16);
    p0.z = h0[4] | (h0[5] << 16); p0.w = h0[6] | (h0[7] << 16);
    p1.x = h1[0] | (h1[1] << 16); p1.y = h1[2] | (h1[3] << 16);
    p1.z = h1[4] | (h1[5] << 16); p1.w = h1[6] | (h1[7] << 16);
    *(uint4*)(Z + (size_t)nd0 * 256 + c * 8) = p0;
    if (nd1 < n) *(uint4*)(Z + (size_t)nd1 * 256 + c * 8) = p1;
  }
}

// ---------------- streaming MFMA SAGE layer (no LDS, no barriers) ----------------
// MODE 0: out = relu(Z@W + b) bf16 -> outB[node*256 + 128 + f] (Z2 root half)
// MODE 1: h = relu(Z@W + b) fp32 regs; s2 = h.w3l, r2 = h.w3r (fused layer 3)
template <int MODE>
__global__ __launch_bounds__(256, 2) void k_sage2(
    const unsigned short* __restrict__ Z, const unsigned short* __restrict__ WTh,
    const unsigned short* __restrict__ WTl, const float* __restrict__ bias,
    unsigned short* __restrict__ outB,
    const float* __restrict__ w3l, const float* __restrict__ w3r,
    float* __restrict__ s2, float* __restrict__ r2, int n) {
  const int tid = threadIdx.x;
  const int lane = tid & 63;
  const int w = tid >> 6;
  const int ln = lane & 15;
  const int r16 = lane >> 4;
  const int m0 = blockIdx.x * 256 + w * 64;

  f32x4 acc[4][8];
  #pragma unroll
  for (int s = 0; s < 4; s++)
    #pragma unroll
    for (int cc = 0; cc < 8; cc++) {
      acc[s][cc][0] = 0.f; acc[s][cc][1] = 0.f;
      acc[s][cc][2] = 0.f; acc[s][cc][3] = 0.f;
    }
  float bv[8];
  #pragma unroll
  for (int cc = 0; cc < 8; cc++) bv[cc] = bias[cc * 16 + ln];

  const size_t wbase = (size_t)ln * 256 + r16 * 8;

  #pragma unroll
  for (int kh = 0; kh < 2; kh++) {
    bf16x8 a[4][4];
    #pragma unroll
    for (int s = 0; s < 4; s++) {
      int row = m0 + s * 16 + ln;
      if (row > n - 1) row = n - 1;
      const unsigned short* zp = Z + (size_t)row * 256 + kh * 128 + r16 * 8;
      #pragma unroll
      for (int ks = 0; ks < 4; ks++) a[s][ks] = *(const bf16x8*)(zp + ks * 32);
    }
    #pragma unroll
    for (int ks = 0; ks < 4; ks++) {
      #pragma unroll
      for (int cg = 0; cg < 4; cg++) {
        bf16x8 bh[2], bl[2];
        #pragma unroll
        for (int j = 0; j < 2; j++) {
          const size_t o = wbase + (size_t)(cg * 2 + j) * 4096 + kh * 128 + ks * 32;
          bh[j] = *(const bf16x8*)(WTh + o);
          bl[j] = *(const bf16x8*)(WTl + o);
        }
        #pragma unroll
        for (int j = 0; j < 2; j++) {
          #pragma unroll
          for (int s = 0; s < 4; s++) {
            acc[s][cg * 2 + j] =
                __builtin_amdgcn_mfma_f32_16x16x32_bf16(a[s][ks], bh[j], acc[s][cg * 2 + j], 0, 0, 0);
            acc[s][cg * 2 + j] =
                __builtin_amdgcn_mfma_f32_16x16x32_bf16(a[s][ks], bl[j], acc[s][cg * 2 + j], 0, 0, 0);
          }
        }
      }
    }
  }

  if (MODE == 0) {
    #pragma unroll
    for (int s = 0; s < 4; s++)
      #pragma unroll
      for (int r = 0; r < 4; r++) {
        int node = m0 + s * 16 + r16 * 4 + r;
        if (node < n) {
          unsigned short* op = outB + (size_t)node * 256 + 128 + ln;
          #pragma unroll
          for (int cc = 0; cc < 8; cc++) {
            float v = fmaxf(acc[s][cc][r] + bv[cc], 0.f);
            op[cc * 16] = f2bf(v);
          }
        }
      }
  } else {
    float wl[8], wr[8];
    #pragma unroll
    for (int cc = 0; cc < 8; cc++) {
      wl[cc] = w3l[cc * 16 + ln];
      wr[cc] = w3r[cc * 16 + ln];
    }
    #pragma unroll
    for (int s = 0; s < 4; s++)
      #pragma unroll
      for (int r = 0; r < 4; r++) {
        float sl = 0.f, sr = 0.f;
        #pragma unroll
        for (int cc = 0; cc < 8; cc++) {
          float v = fmaxf(acc[s][cc][r] + bv[cc], 0.f);
          sl += v * wl[cc];
          sr += v * wr[cc];
        }
        sl += __shfl_xor(sl, 1); sl += __shfl_xor(sl, 2);
        sl += __shfl_xor(sl, 4); sl += __shfl_xor(sl, 8);
        sr += __shfl_xor(sr, 1); sr += __shfl_xor(sr, 2);
        sr += __shfl_xor(sr, 4); sr += __shfl_xor(sr, 8);
        int node = m0 + s * 16 + r16 * 4 + r;
        if (ln == 0 && node < n) {
          s2[node] = sl;
          r2[node] = sr;
        }
      }
  }
}

// ---------------- final scalar aggregation (16 lanes/node) ----------------
__global__ __launch_bounds__(256) void k_out3(const float* __restrict__ s2,
                                              const float* __restrict__ r2,
                                              const int* __restrict__ beg,
                                              const int* __restrict__ deg,
                                              const int* __restrict__ csr,
                                              const float* __restrict__ b3,
                                              float* __restrict__ out, int n) {
  int t = blockIdx.x * blockDim.x + threadIdx.x;
  int node = t >> 4;
  int ln = t & 15;
  if (node >= n) return;
  int bg = beg[node], d = deg[node];
  float s = 0.f;
  for (int i = ln; i < d; i += 16) s += s2[csr[bg + i]];
  s += __shfl_xor(s, 1); s += __shfl_xor(s, 2);
  s += __shfl_xor(s, 4); s += __shfl_xor(s, 8);
  if (ln == 0) out[node] = s / (d > 0 ? (float)d : 1.0f) + r2[node] + b3[0];
}

extern "C" void kernel_launch(void* const* d_in, const int* in_sizes, int n_in,
                              void* d_out, int out_size, void* d_ws, size_t ws_size,
                              hipStream_t stream) {
  const float* x   = (const float*)d_in[0];
  const int*   ei  = (const int*)d_in[1];
  const float* W1l = (const float*)d_in[2];
  const float* W1r = (const float*)d_in[3];
  const float* b1  = (const float*)d_in[4];
  const float* W2l = (const float*)d_in[5];
  const float* W2r = (const float*)d_in[6];
  const float* b2  = (const float*)d_in[7];
  const float* W3l = (const float*)d_in[8];
  const float* W3r = (const float*)d_in[9];
  const float* b3  = (const float*)d_in[10];
  float* out = (float*)d_out;

  const int N = NN;
  const int E = in_sizes[1] / 2;
  const int* src = ei;
  const int* dst = ei + E;

  char* ws = (char*)d_ws;
  size_t off = 0;
  auto alloc = [&](size_t bytes) -> char* {
    char* p = ws + off;
    off = (off + bytes + 255) & ~(size_t)255;
    return p;
  };
  int* cursor = (int*)alloc((NB + 1) * 4);
  unsigned* pairs = (unsigned*)alloc((size_t)NB * SLAB * 4);
  int* csr  = (int*)alloc(((size_t)NB * SLAB + 128) * 4);  // +pad: masked OOB lane reads
  int* beg  = (int*)alloc((size_t)N * 4);
  int* deg  = (int*)alloc((size_t)N * 4);
  float* s2 = (float*)alloc((size_t)N * 4);
  float* r2 = (float*)alloc((size_t)N * 4);
  unsigned short* wt1h = (unsigned short*)alloc(128 * 256 * 2);
  unsigned short* wt1l = (unsigned short*)alloc(128 * 256 * 2);
  unsigned short* wt2h = (unsigned short*)alloc(128 * 256 * 2);
  unsigned short* wt2l = (unsigned short*)alloc(128 * 256 * 2);
  unsigned short* Z1 = (unsigned short*)alloc((size_t)(N + 1) * 256 * 2);
  unsigned short* Z2 = (unsigned short*)alloc((size_t)(N + 1) * 256 * 2);

  hipMemsetAsync(cursor, 0, (NB + 1) * 4, stream);

  // ---- fused prep: edge scatter | x->bf16 | weight split | zero rows ----
  const int SB = (E + 2047) / 2048;         // 782 scatter blocks
  const int XB = N * 16 / 256;              // 6250 cvt_x blocks
  k_prep<<<SB + XB + 64 + 1, 256, 0, stream>>>(
      src, dst, E, SB, cursor, pairs, x, Z1, Z2,
      W1l, W1r, W2l, W2r, wt1h, wt1l, wt2h, wt2l);
  k_build<<<NB, 256, 0, stream>>>(pairs, cursor, beg, deg, csr, N);

  const int nPairs = (N + 1) / 2;                      // 50000 node-pairs
  const int wb = (nPairs * 64 + 255) / 256;            // 12500 blocks
  const int sb = (N + 255) / 256;
  // ---- layer 1 ----
  k_aggZ<<<wb, 256, 0, stream>>>(Z1, beg, deg, csr, nPairs, N);
  k_sage2<0><<<sb, 256, 0, stream>>>(Z1, wt1h, wt1l, b1, Z2,
                                     nullptr, nullptr, nullptr, nullptr, N);
  // ---- layer 2 (+ fused layer-3 transform) ----
  k_aggZ<<<wb, 256, 0, stream>>>(Z2, beg, deg, csr, nPairs, N);
  k_sage2<1><<<sb, 256, 0, stream>>>(Z2, wt2h, wt2l, b2, nullptr,
                                     W3l, W3r, s2, r2, N);
  // ---- layer 3 scalar aggregation ----
  k_out3<<<(N * 16 + 255) / 256, 256, 0, stream>>>(s2, r2, beg, deg, csr, b3, out, N);
}